// Round 1
// baseline (1806.321 us; speedup 1.0000x reference)
//
#include <hip/hip_runtime.h>
#include <hip/hip_bf16.h>

// Problem constants (fixed by setup_inputs):
// x: (4, 256, 32, 32, 32) fp32; qkv_weight: (512, 256); relative: (64, 63);
// gamma/beta: (512,). Output: (4, 256, 32, 32, 32) fp32.
// hc = 32, N_HEAD = 8, SPAN = 32.
//
// Pipeline:
//  K1: qkv[b,o,h,w,t] = sum_c W[o,c]*x[b,c,h,w,t]   (bf16 ws, 128 MB)
//  K2: per (b,head,w): scores(32x32)=qk+qr+kr, softmax, sv/sve; writes
//      stacked[b,head,cs=2c+s, i, w, t] (bf16, 128 MB) + channel sum/sumsq atomics
//  K3: out[b, head*32+c, i, w, t] = BN(sv)+BN(sve)   (fp32, 128 MB)

// ---------------- K1: QKV GEMM (fp32 compute, bf16 store) ----------------
__global__ __launch_bounds__(256) void k1_qkv_gemm(
    const float* __restrict__ Wq, const float* __restrict__ x,
    __hip_bfloat16* __restrict__ qkv) {
  __shared__ float As[16][132];   // [k][m], +4 pad: conflict-free staging, 16B-aligned rows
  __shared__ float Bs[16][128];   // [k][n]
  const int td = threadIdx.x;
  const int bx = blockIdx.x;
  const int ntile = bx & 255;
  const int otile = (bx >> 8) & 3;
  const int b = bx >> 10;
  const int n0 = ntile * 128, o0 = otile * 128;
  const float* xb = x + (size_t)b * 256 * 32768;
  __hip_bfloat16* qb = qkv + (size_t)b * 512 * 32768;

  float acc[8][8] = {{0.f}};
  const int tx = td & 15, ty = td >> 4;

  for (int k0 = 0; k0 < 256; k0 += 16) {
    {  // stage A: W[o0+mm, k0+kk] -> As[kk][mm]; 16 consecutive c per lane group
      const int kk = td & 15, mb = td >> 4;
#pragma unroll
      for (int it = 0; it < 8; ++it) {
        const int mm = mb + 16 * it;
        As[kk][mm] = Wq[(o0 + mm) * 256 + k0 + kk];
      }
    }
    {  // stage B: x rows, float4 coalesced
#pragma unroll
      for (int it = 0; it < 2; ++it) {
        const int f4 = td + 256 * it;          // 512 float4 = 2048 floats
        const int kk = f4 >> 5, nf = f4 & 31;
        *(float4*)&Bs[kk][nf * 4] =
            *(const float4*)&xb[(size_t)(k0 + kk) * 32768 + n0 + nf * 4];
      }
    }
    __syncthreads();
#pragma unroll
    for (int kk = 0; kk < 16; ++kk) {
      float4 a0 = *(const float4*)&As[kk][ty * 8];
      float4 a1 = *(const float4*)&As[kk][ty * 8 + 4];
      float4 b0 = *(const float4*)&Bs[kk][tx * 8];
      float4 b1 = *(const float4*)&Bs[kk][tx * 8 + 4];
      float av[8] = {a0.x, a0.y, a0.z, a0.w, a1.x, a1.y, a1.z, a1.w};
      float bv[8] = {b0.x, b0.y, b0.z, b0.w, b1.x, b1.y, b1.z, b1.w};
#pragma unroll
      for (int i = 0; i < 8; ++i)
#pragma unroll
        for (int j = 0; j < 8; ++j) acc[i][j] += av[i] * bv[j];
    }
    __syncthreads();
  }
#pragma unroll
  for (int i = 0; i < 8; ++i) {
    struct alignas(16) BF8 { __hip_bfloat16 v[8]; } p;
#pragma unroll
    for (int j = 0; j < 8; ++j) p.v[j] = __float2bfloat16(acc[i][j]);
    *(BF8*)(qb + (size_t)(o0 + ty * 8 + i) * 32768 + n0 + tx * 8) = p;
  }
}

// ---------------- K2: attention + stacked write + BN stats ----------------
// block = (b, head, w); 256 thr; t processed in 4 chunks of 8.
// thread <-> (i = td&31, tt = td>>5) during compute.
__global__ __launch_bounds__(256) void k2_attn(
    const __hip_bfloat16* __restrict__ qkv, const float* __restrict__ relative,
    __hip_bfloat16* __restrict__ stacked, float* __restrict__ stats) {
  __shared__ float embs[64 * 64];          // relative rows, stride 64 (cols 0..62 used)
  __shared__ __hip_bfloat16 slab[64 * 32 * 8];  // [c|cs][i][tt]

  const int bx = blockIdx.x;
  const int w = bx & 31, head = (bx >> 5) & 7, b = bx >> 8;
  const int td = threadIdx.x;

  for (int idx = td; idx < 64 * 63; idx += 256) {
    const int c = idx / 63, d = idx - c * 63;
    embs[c * 64 + d] = relative[idx];
  }

  const __hip_bfloat16* qbase =
      qkv + ((size_t)b * 512 + head * 64) * 32768 + w * 32;
  __hip_bfloat16* sbase =
      stacked + ((size_t)(b * 8 + head)) * 64 * 32768 + w * 32;

  float asum[8] = {0.f}, asq[8] = {0.f};
  const int i = td & 31, tt = td >> 5;

  for (int tc = 0; tc < 4; ++tc) {
    const int t0 = tc * 8;
    __syncthreads();  // protect slab from previous chunk's readers
    // stage qkv slab: 8 t's (16B) per (c,i2)
    for (int r = 0; r < 8; ++r) {
      const int idx = td + 256 * r;          // (c = idx>>5, i2 = idx&31)
      *(float4*)&slab[idx * 8] =
          *(const float4*)(qbase + (size_t)idx * 1024 + t0);
    }
    __syncthreads();

    float qv[16], kv[16];
#pragma unroll
    for (int c = 0; c < 16; ++c) {
      qv[c] = __bfloat162float(slab[(c * 32 + i) * 8 + tt]);
      kv[c] = __bfloat162float(slab[((16 + c) * 32 + i) * 8 + tt]);
    }
    // scores: qk + qr + kr
    float s[32];
#pragma unroll
    for (int j = 0; j < 32; ++j) {
      float a = 0.f;
#pragma unroll
      for (int c = 0; c < 16; ++c) {
        const float kj = __bfloat162float(slab[((16 + c) * 32 + j) * 8 + tt]);
        a += qv[c] * (kj + embs[c * 64 + i + j]);
        a += kv[c] * embs[(16 + c) * 64 + i + j];
      }
      s[j] = a;
    }
    // softmax over j
    float m = s[0];
#pragma unroll
    for (int j = 1; j < 32; ++j) m = fmaxf(m, s[j]);
    float sum = 0.f;
#pragma unroll
    for (int j = 0; j < 32; ++j) { s[j] = __expf(s[j] - m); sum += s[j]; }
    const float inv = 1.f / sum;
#pragma unroll
    for (int j = 0; j < 32; ++j) s[j] *= inv;
    // sv, sve
    float sv[32], sve[32];
#pragma unroll
    for (int c = 0; c < 32; ++c) {
      float a0 = 0.f, a1 = 0.f;
#pragma unroll
      for (int j = 0; j < 32; ++j) {
        a0 += s[j] * __bfloat162float(slab[((32 + c) * 32 + j) * 8 + tt]);
        a1 += s[j] * embs[(32 + c) * 64 + i + j];
      }
      sv[c] = a0; sve[c] = a1;
    }
    __syncthreads();  // everyone done reading slab
#pragma unroll
    for (int c = 0; c < 32; ++c) {
      slab[((2 * c) * 32 + i) * 8 + tt] = __float2bfloat16(sv[c]);
      slab[((2 * c + 1) * 32 + i) * 8 + tt] = __float2bfloat16(sve[c]);
    }
    __syncthreads();
    // cooperative 16B global writes + per-thread stat accumulation
    for (int r = 0; r < 8; ++r) {
      const int idx = td + 256 * r;          // cs = idx>>5 = td>>5 + 8r, i2 = idx&31
      const float4 v4 = *(float4*)&slab[idx * 8];
      *(float4*)(sbase + (size_t)idx * 1024 + t0) = v4;
      const __hip_bfloat16* hp = (const __hip_bfloat16*)&v4;
      float ls = 0.f, lq = 0.f;
#pragma unroll
      for (int u = 0; u < 8; ++u) {
        const float f = __bfloat162float(hp[u]);
        ls += f; lq += f * f;
      }
      asum[r] += ls; asq[r] += lq;
    }
  }
  // reduce stats over the 32 lanes sharing cs (lanes of one 32-half), then atomics
#pragma unroll
  for (int r = 0; r < 8; ++r) {
    float ls = asum[r], lq = asq[r];
#pragma unroll
    for (int off = 16; off >= 1; off >>= 1) {
      ls += __shfl_xor(ls, off);
      lq += __shfl_xor(lq, off);
    }
    if ((td & 31) == 0) {
      const int cs = (td >> 5) + 8 * r;
      const int o2 = head * 64 + cs;
      atomicAdd(&stats[o2], ls);
      atomicAdd(&stats[512 + o2], lq);
    }
  }
}

// ---------------- K3: BN finalize + pair-sum + output ----------------
__global__ __launch_bounds__(256) void k3_finalize(
    const __hip_bfloat16* __restrict__ stacked, const float* __restrict__ stats,
    const float* __restrict__ gamma, const float* __restrict__ beta,
    float* __restrict__ out) {
  const size_t g = (size_t)blockIdx.x * 256 + threadIdx.x;
  const size_t e = g * 8;                 // 8 contiguous (w,t) elements
  const int wt = (int)(e & 1023);
  const size_t row = e >> 10;             // (b*256 + c2)*32 + i
  const int i = (int)(row & 31);
  const int bc2 = (int)(row >> 5);
  const int c2 = bc2 & 255;
  const int b = bc2 >> 8;
  const int head = c2 >> 5, c = c2 & 31;

  const size_t s0 = (((size_t)(b * 8 + head) * 64 + 2 * c) * 32 + i) * 1024 + wt;
  const float4 r0 = *(const float4*)(stacked + s0);
  const float4 r1 = *(const float4*)(stacked + s0 + 32768);  // cs+1

  const int o20 = 2 * c2, o21 = 2 * c2 + 1;
  const float NINV = 1.f / 131072.f;
  const float m0 = stats[o20] * NINV, m1 = stats[o21] * NINV;
  const float v0 = stats[512 + o20] * NINV - m0 * m0;
  const float v1 = stats[512 + o21] * NINV - m1 * m1;
  const float sc0 = gamma[o20] * rsqrtf(v0 + 1e-5f);
  const float sc1 = gamma[o21] * rsqrtf(v1 + 1e-5f);
  const float sh0 = beta[o20] - m0 * sc0 + beta[o21] - m1 * sc1;  // combined shifts

  const __hip_bfloat16* h0 = (const __hip_bfloat16*)&r0;
  const __hip_bfloat16* h1 = (const __hip_bfloat16*)&r1;
  float res[8];
#pragma unroll
  for (int u = 0; u < 8; ++u)
    res[u] = __bfloat162float(h0[u]) * sc0 + __bfloat162float(h1[u]) * sc1 + sh0;
  *(float4*)(out + e) = make_float4(res[0], res[1], res[2], res[3]);
  *(float4*)(out + e + 4) = make_float4(res[4], res[5], res[6], res[7]);
}

extern "C" void kernel_launch(void* const* d_in, const int* in_sizes, int n_in,
                              void* d_out, int out_size, void* d_ws, size_t ws_size,
                              hipStream_t stream) {
  const float* x        = (const float*)d_in[0];
  const float* qkv_w    = (const float*)d_in[1];
  const float* relative = (const float*)d_in[2];
  const float* gamma    = (const float*)d_in[3];
  const float* beta     = (const float*)d_in[4];
  float* out = (float*)d_out;

  __hip_bfloat16* qkv = (__hip_bfloat16*)d_ws;               // 67,108,864 bf16 = 128 MB
  __hip_bfloat16* stacked = qkv + (size_t)67108864;          // 128 MB
  float* stats = (float*)(stacked + (size_t)67108864);       // 1024 fp32

  hipMemsetAsync(stats, 0, 1024 * sizeof(float), stream);
  k1_qkv_gemm<<<dim3(4096), dim3(256), 0, stream>>>(qkv_w, x, qkv);
  k2_attn<<<dim3(1024), dim3(256), 0, stream>>>(qkv, relative, stacked, stats);
  k3_finalize<<<dim3(16384), dim3(256), 0, stream>>>(stacked, stats, gamma, beta, out);
}

// Round 2
// 851.602 us; speedup vs baseline: 2.1211x; 2.1211x over previous
//
#include <hip/hip_runtime.h>
#include <hip/hip_bf16.h>

// x: (4, 256, 32, 32, 32) fp32; qkv_weight: (512, 256); relative: (64, 63);
// gamma/beta: (512,). Output: (4, 256, 32, 32, 32) fp32.
//
// K1: qkv[b,o,(h,w,t)] = sum_c W[o,c]*x[b,c,(h,w,t)]  (bf16 ws, 128 MB)
// K2: MFMA attention per (b,head,w): qk/qr/kr via 32x32x16 bf16 MFMA,
//     softmax sums via ones-MFMA (no max-sub: |scores| ~ 25 max, exp fits f32),
//     sv/sve via MFMA; writes stk2[bh][w][i][t][c-dword(sv,sve)] + BN stat atomics
// K3: BN finalize + pair-sum, LDS transpose for coalesced out writes

typedef __attribute__((ext_vector_type(8))) short short8;
typedef __attribute__((ext_vector_type(16))) float f32x16;

__device__ inline unsigned short f2bu(float f) {
  __hip_bfloat16 h = __float2bfloat16(f);
  return *(unsigned short*)&h;
}

#define MFMA32(A, B, C) __builtin_amdgcn_mfma_f32_32x32x16_bf16(A, B, C, 0, 0, 0)

// slab padding: [i][ch][tt]  addr = i*S_I + ch*S_C + tt
// S_I=646 elems (323 dw, mod32=3 -> conflict-free i-strided reads)
// S_C=10 elems (5 dw, mod32=5 -> conflict-free ch-strided reads)
constexpr int S_I = 646;
constexpr int S_C = 10;

// ---------------- K1: QKV GEMM (fp32 compute, bf16 store) — unchanged ----------------
__global__ __launch_bounds__(256) void k1_qkv_gemm(
    const float* __restrict__ Wq, const float* __restrict__ x,
    __hip_bfloat16* __restrict__ qkv) {
  __shared__ float As[16][132];
  __shared__ float Bs[16][128];
  const int td = threadIdx.x;
  const int bx = blockIdx.x;
  const int ntile = bx & 255;
  const int otile = (bx >> 8) & 3;
  const int b = bx >> 10;
  const int n0 = ntile * 128, o0 = otile * 128;
  const float* xb = x + (size_t)b * 256 * 32768;
  __hip_bfloat16* qb = qkv + (size_t)b * 512 * 32768;

  float acc[8][8] = {{0.f}};
  const int tx = td & 15, ty = td >> 4;

  for (int k0 = 0; k0 < 256; k0 += 16) {
    {
      const int kk = td & 15, mb = td >> 4;
#pragma unroll
      for (int it = 0; it < 8; ++it) {
        const int mm = mb + 16 * it;
        As[kk][mm] = Wq[(o0 + mm) * 256 + k0 + kk];
      }
    }
    {
#pragma unroll
      for (int it = 0; it < 2; ++it) {
        const int f4 = td + 256 * it;
        const int kk = f4 >> 5, nf = f4 & 31;
        *(float4*)&Bs[kk][nf * 4] =
            *(const float4*)&xb[(size_t)(k0 + kk) * 32768 + n0 + nf * 4];
      }
    }
    __syncthreads();
#pragma unroll
    for (int kk = 0; kk < 16; ++kk) {
      float4 a0 = *(const float4*)&As[kk][ty * 8];
      float4 a1 = *(const float4*)&As[kk][ty * 8 + 4];
      float4 b0 = *(const float4*)&Bs[kk][tx * 8];
      float4 b1 = *(const float4*)&Bs[kk][tx * 8 + 4];
      float av[8] = {a0.x, a0.y, a0.z, a0.w, a1.x, a1.y, a1.z, a1.w};
      float bv[8] = {b0.x, b0.y, b0.z, b0.w, b1.x, b1.y, b1.z, b1.w};
#pragma unroll
      for (int i = 0; i < 8; ++i)
#pragma unroll
        for (int j = 0; j < 8; ++j) acc[i][j] += av[i] * bv[j];
    }
    __syncthreads();
  }
#pragma unroll
  for (int i = 0; i < 8; ++i) {
    struct alignas(16) BF8 { __hip_bfloat16 v[8]; } p;
#pragma unroll
    for (int j = 0; j < 8; ++j) p.v[j] = __float2bfloat16(acc[i][j]);
    *(BF8*)(qb + (size_t)(o0 + ty * 8 + i) * 32768 + n0 + tx * 8) = p;
  }
}

// ---------------- K2: MFMA attention ----------------
// block = (b, head, w); 4 waves; t in 4 chunks of 8; wave handles 2 t-problems/chunk.
__global__ __launch_bounds__(256, 3) void k2_attn_mfma(
    const __hip_bfloat16* __restrict__ qkv, const float* __restrict__ rel,
    unsigned int* __restrict__ stk2, float* __restrict__ stats) {
  __shared__ __align__(16) __hip_bfloat16 slab[20672];      // [i][ch][tt] padded
  __shared__ __align__(16) unsigned short Sbuf[4 * 1280];   // per-wave sim [32][40] bf16
  __shared__ float statb[4][32][4];

  const int bx = blockIdx.x;
  const int w = bx & 31, head = (bx >> 5) & 7, b = bx >> 8;
  const int td = threadIdx.x;
  const int wid = td >> 6, l = td & 63, h = l >> 5, n = l & 31;

  // emb fragments (B-layout: lane n holds k-range (h*8..h*8+7)), bf16
  short8 eqf[2], ekf[2], evf[4];
#pragma unroll
  for (int dt = 0; dt < 2; ++dt)
#pragma unroll
    for (int e = 0; e < 8; ++e) {
      int c = h * 8 + e, d = dt * 32 + n;
      eqf[dt][e] = (d < 63) ? (short)f2bu(rel[c * 63 + d]) : (short)0;
      ekf[dt][e] = (d < 63) ? (short)f2bu(rel[(16 + c) * 63 + d]) : (short)0;
    }
#pragma unroll
  for (int kh = 0; kh < 4; ++kh)
#pragma unroll
    for (int e = 0; e < 8; ++e) {
      int d = kh * 16 + h * 8 + e;
      evf[kh][e] = (d < 63) ? (short)f2bu(rel[(32 + n) * 63 + d]) : (short)0;
    }
  short8 ones;
#pragma unroll
  for (int e = 0; e < 8; ++e) ones[e] = (short)0x3F80;  // bf16 1.0

  const __hip_bfloat16* qbase = qkv + ((size_t)(b * 512 + head * 64)) * 32768 + w * 32;
  unsigned int* sb = stk2 + ((size_t)((b * 8 + head) * 32 + w)) * 32768;
  unsigned short* Sb = Sbuf + wid * 1280;

  const f32x16 zf = {0, 0, 0, 0, 0, 0, 0, 0, 0, 0, 0, 0, 0, 0, 0, 0};
  float st0 = 0, st1 = 0, st2 = 0, st3 = 0;

  for (int tc = 0; tc < 4; ++tc) {
    const int t0 = tc * 8;
    __syncthreads();  // previous chunk's readers done
    for (int r = 0; r < 8; ++r) {
      int idx = td + 256 * r;  // ch = idx>>5, i = idx&31
      const uint4 dat = *(const uint4*)(qbase + (size_t)idx * 1024 + t0);
      unsigned int* lp = (unsigned int*)(slab + (idx & 31) * S_I + (idx >> 5) * S_C);
      lp[0] = dat.x; lp[1] = dat.y; lp[2] = dat.z; lp[3] = dat.w;
    }
    __syncthreads();
    for (int u = 0; u < 2; ++u) {
      const int tt = 2 * wid + u;
      const int t = t0 + tt;
      // A-frags: lane m=n holds 8 channel-values (k-range h*8+e)
      short8 aq, ak;
#pragma unroll
      for (int e = 0; e < 8; ++e) {
        aq[e] = *(const short*)&slab[n * S_I + (h * 8 + e) * S_C + tt];
        ak[e] = *(const short*)&slab[n * S_I + (16 + h * 8 + e) * S_C + tt];
      }
      f32x16 qkD = MFMA32(aq, ak, zf);        // D[i][j] = sum_c q[c,i]k[c,j]
      f32x16 Rq0 = MFMA32(aq, eqf[0], zf);    // Rq[i][d], d-tiles
      f32x16 Rq1 = MFMA32(aq, eqf[1], zf);
      f32x16 Rk0 = MFMA32(ak, ekf[0], zf);
      f32x16 Rk1 = MFMA32(ak, ekf[1], zf);
      // scores: s = qk + Rq[i][i+j] + Rk[i][i+j]; exp (no max-sub); write sim bf16
#pragma unroll
      for (int r = 0; r < 16; ++r) {
        int rowr = (r & 3) + 8 * (r >> 2) + 4 * h;
        int d = rowr + n;                 // i + j, <= 62
        int src = (d & 31) + 32 * h;      // source lane within my half
        float vq0 = __shfl(Rq0[r], src);
        float vq1 = __shfl(Rq1[r], src);
        float vk0 = __shfl(Rk0[r], src);
        float vk1 = __shfl(Rk1[r], src);
        float s = qkD[r] + (d < 32 ? vq0 + vk0 : vq1 + vk1);
        Sb[rowr * 40 + n] = f2bu(__expf(s));
      }
      // v B-frags: lane n=c holds v[c][j-range]
      short8 bv0, bv1;
#pragma unroll
      for (int e = 0; e < 8; ++e) {
        int j0 = h * 8 + e, j1 = 16 + h * 8 + e;
        bv0[e] = *(const short*)&slab[j0 * S_I + (32 + n) * S_C + tt];
        bv1[e] = *(const short*)&slab[j1 * S_I + (32 + n) * S_C + tt];
      }
      // sim A-frags (aligned b128)
      short8 as0 = *(const short8*)(Sb + n * 40 + h * 8);
      short8 as1 = *(const short8*)(Sb + n * 40 + 16 + h * 8);
      f32x16 svD = MFMA32(as1, bv1, MFMA32(as0, bv0, zf));
      f32x16 sumD = MFMA32(as1, ones, MFMA32(as0, ones, zf));  // row sums of exp
      // sve: shifted-sim A-frags (Psh[i][d] = sim[i][d-i], 0 outside)
      f32x16 sveD = zf;
#pragma unroll
      for (int kh = 0; kh < 4; ++kh) {
        short8 ap;
#pragma unroll
        for (int e = 0; e < 8; ++e) {
          int k = kh * 16 + h * 8 + e;
          int jj = k - n;  // d - i
          unsigned short raw = Sb[n * 40 + (jj & 31)];
          ap[e] = ((unsigned)jj < 32u) ? (short)raw : (short)0;
        }
        sveD = MFMA32(ap, evf[kh], sveD);
      }
      // epilogue: normalize, stats, packed coalesced store
#pragma unroll
      for (int r = 0; r < 16; ++r) {
        int rowr = (r & 3) + 8 * (r >> 2) + 4 * h;
        float inv = 1.0f / sumD[r];
        float svn = svD[r] * inv, sven = sveD[r] * inv;
        st0 += svn; st1 += svn * svn; st2 += sven; st3 += sven * sven;
        unsigned int pk = (unsigned int)f2bu(svn) | ((unsigned int)f2bu(sven) << 16);
        sb[((size_t)rowr * 32 + t) * 32 + n] = pk;
      }
    }
  }
  // stats: fold halves (lane^32 shares c), per-block LDS reduce, 128 atomics/block
  st0 += __shfl_xor(st0, 32); st1 += __shfl_xor(st1, 32);
  st2 += __shfl_xor(st2, 32); st3 += __shfl_xor(st3, 32);
  if (h == 0) {
    statb[wid][n][0] = st0; statb[wid][n][1] = st1;
    statb[wid][n][2] = st2; statb[wid][n][3] = st3;
  }
  __syncthreads();
  if (td < 32) {
    float a0 = 0, a1 = 0, a2 = 0, a3 = 0;
    for (int wv = 0; wv < 4; ++wv) {
      a0 += statb[wv][td][0]; a1 += statb[wv][td][1];
      a2 += statb[wv][td][2]; a3 += statb[wv][td][3];
    }
    const int o2 = head * 64 + 2 * td;
    atomicAdd(&stats[o2], a0);
    atomicAdd(&stats[o2 + 1], a2);
    atomicAdd(&stats[512 + o2], a1);
    atomicAdd(&stats[512 + o2 + 1], a3);
  }
}

// ---------------- K3: BN finalize + pair-sum, LDS transpose ----------------
__global__ __launch_bounds__(256) void k3_finalize2(
    const unsigned int* __restrict__ stk2, const float* __restrict__ stats,
    const float* __restrict__ gamma, const float* __restrict__ beta,
    float* __restrict__ out) {
  __shared__ float trans[32][33];
  __shared__ float s_sc[64], s_sh[64];
  const int bx = blockIdx.x;
  const int w = bx & 31, head = (bx >> 5) & 7, b = bx >> 8;
  const int td = threadIdx.x;
  if (td < 64) {
    const int o2 = head * 64 + td;
    const float NINV = 1.f / 131072.f;
    float m = stats[o2] * NINV;
    float v = stats[512 + o2] * NINV - m * m;
    float sc = gamma[o2] * rsqrtf(v + 1e-5f);
    s_sc[td] = sc;
    s_sh[td] = beta[o2] - m * sc;
  }
  __syncthreads();
  const unsigned int* pb = stk2 + ((size_t)((b * 8 + head) * 32 + w)) * 32768;
  float* ob = out + ((size_t)(b * 256 + head * 32)) * 32768 + w * 32;
  const int t = td >> 3, c0 = (td & 7) * 4;
  for (int i = 0; i < 32; ++i) {
    const uint4 dat = *(const uint4*)(pb + (size_t)i * 1024 + td * 4);
    unsigned int dws[4] = {dat.x, dat.y, dat.z, dat.w};
#pragma unroll
    for (int q = 0; q < 4; ++q) {
      int c = c0 + q;
      float sv = __uint_as_float((dws[q] & 0xFFFFu) << 16);
      float sve = __uint_as_float(dws[q] & 0xFFFF0000u);
      trans[c][t] = sv * s_sc[2 * c] + sve * s_sc[2 * c + 1] + s_sh[2 * c] + s_sh[2 * c + 1];
    }
    __syncthreads();
    {
      const int t2 = td & 31;
#pragma unroll
      for (int cc = 0; cc < 4; ++cc) {
        int c = (td >> 5) + 8 * cc;
        ob[(size_t)c * 32768 + (size_t)i * 1024 + t2] = trans[c][t2];
      }
    }
    __syncthreads();
  }
}

extern "C" void kernel_launch(void* const* d_in, const int* in_sizes, int n_in,
                              void* d_out, int out_size, void* d_ws, size_t ws_size,
                              hipStream_t stream) {
  const float* x        = (const float*)d_in[0];
  const float* qkv_w    = (const float*)d_in[1];
  const float* relative = (const float*)d_in[2];
  const float* gamma    = (const float*)d_in[3];
  const float* beta     = (const float*)d_in[4];
  float* out = (float*)d_out;

  __hip_bfloat16* qkv = (__hip_bfloat16*)d_ws;                 // 128 MB
  unsigned int* stk2 = (unsigned int*)((char*)d_ws + (size_t)134217728);  // 128 MB
  float* stats = (float*)((char*)d_ws + (size_t)268435456);    // 4 KB

  hipMemsetAsync(stats, 0, 1024 * sizeof(float), stream);
  k1_qkv_gemm<<<dim3(4096), dim3(256), 0, stream>>>(qkv_w, x, qkv);
  k2_attn_mfma<<<dim3(1024), dim3(256), 0, stream>>>(qkv, relative, stk2, stats);
  k3_finalize2<<<dim3(1024), dim3(256), 0, stream>>>(stk2, stats, gamma, beta, out);
}